// Round 6
// baseline (1201.098 us; speedup 1.0000x reference)
//
#include <hip/hip_runtime.h>
#include <hip/hip_bf16.h>

typedef _Float16 half8 __attribute__((ext_vector_type(8)));
typedef float f32x4 __attribute__((ext_vector_type(4)));

#define Bsz 32
#define Nseq 2048
#define Edim 1024
#define Hdim 1024

// async global->LDS, 16B per lane. LDS dest = wave-uniform base + lane*16.
__device__ __forceinline__ void gload_lds16(const void* g, void* l) {
    __builtin_amdgcn_global_load_lds(
        (const __attribute__((address_space(1))) unsigned int*)g,
        (__attribute__((address_space(3))) unsigned int*)l, 16, 0, 0);
}

// ---------------- kernel 1a: dw[b,h] = dec[b,:] @ w_d[:,h]  (f32) ------------
__global__ void k_dw(const float* __restrict__ dec, const float* __restrict__ w_d,
                     float* __restrict__ dw) {
    int b = blockIdx.x;
    int h = blockIdx.y * 256 + threadIdx.x;
    const float* dr = dec + b * 1024;
    float a0 = 0.f, a1 = 0.f, a2 = 0.f, a3 = 0.f;
    for (int d = 0; d < 1024; d += 4) {
        a0 += dr[d + 0] * w_d[(d + 0) * 1024 + h];
        a1 += dr[d + 1] * w_d[(d + 1) * 1024 + h];
        a2 += dr[d + 2] * w_d[(d + 2) * 1024 + h];
        a3 += dr[d + 3] * w_d[(d + 3) * 1024 + h];
    }
    dw[b * 1024 + h] = (a0 + a1) + (a2 + a3);
}

// ------- kernel 1b: split w_e (f32 [E][H]) into fp16 hi/lo, transposed [H][E] -
__global__ void k_split(const float* __restrict__ w_e,
                        _Float16* __restrict__ w_hiT, _Float16* __restrict__ w_loT) {
    __shared__ _Float16 th[32][33];
    __shared__ _Float16 tl[32][33];
    int e0 = blockIdx.x * 32, h0 = blockIdx.y * 32;
    int tx = threadIdx.x & 31, ty = threadIdx.x >> 5;
#pragma unroll
    for (int i = 0; i < 4; ++i) {
        int r = ty + i * 8;
        float x = w_e[(size_t)(e0 + r) * 1024 + h0 + tx];
        _Float16 h = (_Float16)x;
        th[r][tx] = h;
        tl[r][tx] = (_Float16)(x - (float)h);
    }
    __syncthreads();
#pragma unroll
    for (int i = 0; i < 4; ++i) {
        int r = ty + i * 8;
        w_hiT[(size_t)(h0 + r) * 1024 + e0 + tx] = th[tx][r];
        w_loT[(size_t)(h0 + r) * 1024 + e0 + tx] = tl[tx][r];
    }
}

// ---------------- kernel 2: scores[m] = sum_h w_out[h]*tanh((enc@w_e)[m,h]+dw[b,h])
// fp16x3 split MFMA, 16x16x32. 1024 thr (16 waves, 4x4 wave grid).
// M_TILE=256, H_CHUNK=256, K_STEP=32, flat tile loop t=0..127 (hc=t>>5, kt=t&31).
//
// r4-proven single-barrier full-dbuf structure (compiler-scheduled; NO manual
// waitcnt/sched_barrier - that was the r5 regression), scaled 2x in M to double
// MFMA work per barrier window (192 MFMA/SIMD vs fixed ~2.7k-cycle stage+drain
// overhead). Grid = 256 = exactly 1 block/CU.
//
// Per tile: issue B gload_lds(t+1 -> buf^1) [1 instr/array: 1024 lanes x 16B
// = full 16KB tile] | convert+ds_write A(t+1) | A raw loads(t+2) | ds_read
// frags(cur) | 48 MFMA/wave | one __syncthreads (drains everything).
//
// Dynamic LDS 132 KB:
//   A hi/lo buf0: 0 / 16384       A hi/lo buf1: 32768 / 49152   ([4ks][256][16B])
//   B hi/lo buf0: 65536 / 81920   B hi/lo buf1: 98304 / 114688  ([4ks][256][16B])
//   scoreL: 131072 (256 f32)
__global__ __launch_bounds__(1024, 1)
void k_scores(const float* __restrict__ enc,
              const _Float16* __restrict__ w_hiT, const _Float16* __restrict__ w_loT,
              const float* __restrict__ dw, const float* __restrict__ w_out,
              float* __restrict__ scores) {
    extern __shared__ __align__(16) char smem[];
    float* scoreL = (float*)(smem + 131072);

    const int tid  = threadIdx.x;
    const int lane = tid & 63;
    const int wave = tid >> 6;
    const int wr = wave >> 2, wc = wave & 3;     // 4 x 4 wave grid
    const int m0 = blockIdx.x * 256;
    const int bb = m0 >> 11;                     // 2048 rows per batch; 256|2048
    const float* dwb = dw + bb * 1024;

    // A staging: thread loads 8 f32 of row a_row, kseg a_ks
    const int a_row = tid >> 2, a_ks = tid & 3;
    const float* aBase = enc + (size_t)(m0 + a_row) * 1024 + a_ks * 8;
    // B staging via gload_lds: lds byte = tid*16 = (tid>>8)*4096 + (tid&255)*16
    const int b_row = tid & 255, b_ks = tid >> 8;
    const _Float16* bhBase = w_hiT + (size_t)b_row * 1024 + b_ks * 8;
    const _Float16* blBase = w_loT + (size_t)b_row * 1024 + b_ks * 8;
    const int wofs = wave * 1024;    // per-wave uniform LDS chunk (64 lanes x 16B)

    float sc[4][4];
#pragma unroll
    for (int m = 0; m < 4; ++m)
#pragma unroll
        for (int r = 0; r < 4; ++r) sc[m][r] = 0.f;
    if (tid < 256) scoreL[tid] = 0.f;

    f32x4 acc[4][4];
#pragma unroll
    for (int m = 0; m < 4; ++m)
#pragma unroll
        for (int n = 0; n < 4; ++n) acc[m][n] = (f32x4){0.f, 0.f, 0.f, 0.f};

    float4 pa0, pa1;   // raw A prefetch regs (tile t+1)

#define A_LOAD(t) do { \
        const float* _p = aBase + (((t) & 31) << 5); \
        pa0 = ((const float4*)_p)[0]; \
        pa1 = ((const float4*)_p)[1]; \
    } while (0)
#define B_ISSUE(t, buf) do { \
        const size_t _g = ((size_t)((t) >> 5) << 18) + (size_t)(((t) & 31) << 5); \
        char* _b = smem + 65536 + (buf) * 32768; \
        gload_lds16(bhBase + _g, _b + wofs); \
        gload_lds16(blBase + _g, _b + 16384 + wofs); \
    } while (0)
#define A_STAGE(buf) do { \
        float _q[8] = {pa0.x, pa0.y, pa0.z, pa0.w, pa1.x, pa1.y, pa1.z, pa1.w}; \
        half8 _hi, _lo; \
        _Pragma("unroll") \
        for (int _j = 0; _j < 8; ++_j) { \
            _Float16 _h = (_Float16)_q[_j]; \
            _hi[_j] = _h; \
            _lo[_j] = (_Float16)(_q[_j] - (float)_h); \
        } \
        char* _a = smem + (buf) * 32768; \
        *(half8*)(_a + a_ks * 4096 + a_row * 16) = _hi; \
        *(half8*)(_a + 16384 + a_ks * 4096 + a_row * 16) = _lo; \
    } while (0)

    // prologue: stage tile 0 into buf0, prefetch A(1)
    A_LOAD(0);
    B_ISSUE(0, 0);
    A_STAGE(0);        // waits its own loads (compiler vmcnt), writes Abuf0
    A_LOAD(1);
    __syncthreads();   // drains B(0) gloads too

    const int ks = lane >> 4, rb = lane & 15;

    for (int t = 0; t < 128; ++t) {
        const int cur = t & 1;
        if (t < 127) {
            B_ISSUE(t + 1, cur ^ 1);   // async, lands under the MFMAs below
            A_STAGE(cur ^ 1);          // convert A(t+1) from pa, write LDS
            if (t < 126) A_LOAD(t + 2);
        }
        // ---- fragments from buf cur ----
        const char* sa = smem + cur * 32768;
        const char* sb = smem + 65536 + cur * 32768;
        half8 ah[4], al[4], bh[4], bl[4];
#pragma unroll
        for (int m = 0; m < 4; ++m) {
            int off = ks * 4096 + (wr * 64 + m * 16 + rb) * 16;
            ah[m] = *(const half8*)(sa + off);
            al[m] = *(const half8*)(sa + 16384 + off);
        }
#pragma unroll
        for (int n = 0; n < 4; ++n) {
            int off = ks * 4096 + (wc * 64 + n * 16 + rb) * 16;
            bh[n] = *(const half8*)(sb + off);
            bl[n] = *(const half8*)(sb + 16384 + off);
        }
        __builtin_amdgcn_s_setprio(1);
#pragma unroll
        for (int m = 0; m < 4; ++m)
#pragma unroll
            for (int n = 0; n < 4; ++n) {
                acc[m][n] = __builtin_amdgcn_mfma_f32_16x16x32_f16(ah[m], bh[n], acc[m][n], 0, 0, 0);
                acc[m][n] = __builtin_amdgcn_mfma_f32_16x16x32_f16(ah[m], bl[n], acc[m][n], 0, 0, 0);
                acc[m][n] = __builtin_amdgcn_mfma_f32_16x16x32_f16(al[m], bh[n], acc[m][n], 0, 0, 0);
            }
        __builtin_amdgcn_s_setprio(0);

        if ((t & 31) == 31) {
            // epilogue for hc = t>>5: branch-free tanh + w_out; reset acc
            const int h0 = (t >> 5) << 8;
#pragma unroll
            for (int m = 0; m < 4; ++m)
#pragma unroll
                for (int n = 0; n < 4; ++n) {
                    int h = h0 + wc * 64 + n * 16 + rb;
                    float dwv = dwb[h];
                    float wo  = w_out[h];
#pragma unroll
                    for (int r = 0; r < 4; ++r) {
                        float x = acc[m][n][r] + dwv;
                        float e = __expf(2.0f * fabsf(x));
                        float th = copysignf(1.0f - __fdividef(2.0f, e + 1.0f), x);
                        sc[m][r] += th * wo;
                    }
                    acc[m][n] = (f32x4){0.f, 0.f, 0.f, 0.f};
                }
        }
        __syncthreads();   // drain vm+lgkm: tile t+1 fully staged; cur freed
    }

    // reduce across the 16 col-lanes, then across the 4 wave-cols via LDS atomics
#pragma unroll
    for (int m = 0; m < 4; ++m) {
#pragma unroll
        for (int r = 0; r < 4; ++r) {
            float v = sc[m][r];
            v += __shfl_xor(v, 1);
            v += __shfl_xor(v, 2);
            v += __shfl_xor(v, 4);
            v += __shfl_xor(v, 8);
            sc[m][r] = v;
        }
        if ((lane & 15) == 0) {
            int rbase = wr * 64 + m * 16 + (lane >> 4) * 4;
#pragma unroll
            for (int r = 0; r < 4; ++r)
                atomicAdd(&scoreL[rbase + r], sc[m][r]);
        }
    }
    __syncthreads();
    if (tid < 256) scores[m0 + tid] = scoreL[tid];
#undef A_LOAD
#undef B_ISSUE
#undef A_STAGE
}

// ---------------- kernel 3: masked softmax over N per batch ----------------
// mask is bool in python -> pushed as int32.
__global__ void k_softmax(const float* __restrict__ scores,
                          const int* __restrict__ mask,
                          float* __restrict__ probs, float* __restrict__ out_probs) {
    int b = blockIdx.x, tid = threadIdx.x;
    __shared__ float red[8];
    float v[8];
    float m = -INFINITY;
#pragma unroll
    for (int i = 0; i < 8; ++i) {
        int n = tid + i * 256;
        float s = scores[b * 2048 + n];
        s = (mask[b * 2048 + n] != 0) ? s : -INFINITY;
        v[i] = s;
        m = fmaxf(m, s);
    }
    for (int off = 32; off; off >>= 1) m = fmaxf(m, __shfl_xor(m, off));
    if ((tid & 63) == 0) red[tid >> 6] = m;
    __syncthreads();
    m = fmaxf(fmaxf(red[0], red[1]), fmaxf(red[2], red[3]));
    float sum = 0.f;
#pragma unroll
    for (int i = 0; i < 8; ++i) {
        v[i] = expf(v[i] - m);
        sum += v[i];
    }
    for (int off = 32; off; off >>= 1) sum += __shfl_xor(sum, off);
    if ((tid & 63) == 0) red[4 + (tid >> 6)] = sum;
    __syncthreads();
    sum = red[4] + red[5] + red[6] + red[7];
    float inv = 1.0f / sum;
#pragma unroll
    for (int i = 0; i < 8; ++i) {
        int n = tid + i * 256;
        float p = v[i] * inv;
        probs[b * 2048 + n]     = p;
        out_probs[b * 2048 + n] = p;
    }
}

// ---------------- kernel 4: attn[b,e] += sum_n probs[b,n]*enc[b,n,e] --------
// Survivor compaction (softmax is near-one-hot), then unconditional FMA loop.
__global__ void k_attn(const float* __restrict__ probs, const float* __restrict__ enc,
                       float* __restrict__ attn) {
    __shared__ float pv[128];
    __shared__ int   pidx[128];
    __shared__ int   cnt;
    int b = blockIdx.x, c = blockIdx.y, t = threadIdx.x;
    if (t == 0) cnt = 0;
    __syncthreads();
    if (t < 128) {
        float p = probs[b * 2048 + c * 128 + t];
        if (p >= 1e-12f) {
            int slot = atomicAdd(&cnt, 1);
            pv[slot]   = p;
            pidx[slot] = c * 128 + t;
        }
    }
    __syncthreads();
    int nk = cnt;
    if (nk == 0) return;
    const float* eb = enc + (size_t)b * 2048 * 1024;
    float4 acc = {0.f, 0.f, 0.f, 0.f};
    for (int i = 0; i < nk; ++i) {
        float p = pv[i];
        float4 v = ((const float4*)(eb + (size_t)pidx[i] * 1024))[t];
        acc.x += p * v.x;
        acc.y += p * v.y;
        acc.z += p * v.z;
        acc.w += p * v.w;
    }
    float* o = attn + b * 1024 + t * 4;
    atomicAdd(o + 0, acc.x);
    atomicAdd(o + 1, acc.y);
    atomicAdd(o + 2, acc.z);
    atomicAdd(o + 3, acc.w);
}

extern "C" void kernel_launch(void* const* d_in, const int* in_sizes, int n_in,
                              void* d_out, int out_size, void* d_ws, size_t ws_size,
                              hipStream_t stream) {
    const float* enc   = (const float*)d_in[0];  // [32,2048,1024]
    const float* dec   = (const float*)d_in[1];  // [32,1024]
    const int*   mask  = (const int*)d_in[2];    // [32,2048] bool -> int32
    const float* w_e   = (const float*)d_in[3];  // [1024,1024]
    const float* w_d   = (const float*)d_in[4];  // [1024,1024]
    const float* w_out = (const float*)d_in[5];  // [1024]

    float* out_attn  = (float*)d_out;              // [32*1024]
    float* out_probs = out_attn + Bsz * Hdim;      // [32*2048]

    float* dw        = (float*)d_ws;               // 32*1024
    float* scores    = dw + Bsz * Hdim;            // 32*2048
    float* probs     = scores + Bsz * Nseq;        // 32*2048
    _Float16* w_hiT  = (_Float16*)(probs + Bsz * Nseq);  // [1024*1024]
    _Float16* w_loT  = w_hiT + Edim * Hdim;

    static const int kScoresLds = 132096;   // 128 KB bufs + 1 KB scoreL
    hipFuncSetAttribute((const void*)k_scores,
                        hipFuncAttributeMaxDynamicSharedMemorySize, kScoresLds);

    hipMemsetAsync(out_attn, 0, Bsz * Hdim * sizeof(float), stream);
    k_dw<<<dim3(32, 4), dim3(256), 0, stream>>>(dec, w_d, dw);
    k_split<<<dim3(32, 32), dim3(256), 0, stream>>>(w_e, w_hiT, w_loT);
    k_scores<<<dim3(256), dim3(1024), kScoresLds, stream>>>(enc, w_hiT, w_loT, dw, w_out, scores);
    k_softmax<<<dim3(32), dim3(256), 0, stream>>>(scores, mask, probs, out_probs);
    k_attn<<<dim3(32, 16), dim3(256), 0, stream>>>(probs, enc, out_attn);
}

// Round 7
// 496.329 us; speedup vs baseline: 2.4200x; 2.4200x over previous
//
#include <hip/hip_runtime.h>
#include <hip/hip_bf16.h>

typedef _Float16 half8 __attribute__((ext_vector_type(8)));
typedef float f32x4 __attribute__((ext_vector_type(4)));

#define Bsz 32
#define Nseq 2048
#define Edim 1024
#define Hdim 1024

// async global->LDS, 16B per lane. LDS dest = wave-uniform base + lane*16.
__device__ __forceinline__ void gload_lds16(const void* g, void* l) {
    __builtin_amdgcn_global_load_lds(
        (const __attribute__((address_space(1))) unsigned int*)g,
        (__attribute__((address_space(3))) unsigned int*)l, 16, 0, 0);
}

// ---------------- kernel 1a: dw[b,h] = dec[b,:] @ w_d[:,h]  (f32) ------------
__global__ void k_dw(const float* __restrict__ dec, const float* __restrict__ w_d,
                     float* __restrict__ dw) {
    int b = blockIdx.x;
    int h = blockIdx.y * 256 + threadIdx.x;
    const float* dr = dec + b * 1024;
    float a0 = 0.f, a1 = 0.f, a2 = 0.f, a3 = 0.f;
    for (int d = 0; d < 1024; d += 4) {
        a0 += dr[d + 0] * w_d[(d + 0) * 1024 + h];
        a1 += dr[d + 1] * w_d[(d + 1) * 1024 + h];
        a2 += dr[d + 2] * w_d[(d + 2) * 1024 + h];
        a3 += dr[d + 3] * w_d[(d + 3) * 1024 + h];
    }
    dw[b * 1024 + h] = (a0 + a1) + (a2 + a3);
}

// ------- kernel 1b: split w_e (f32 [E][H]) into fp16 hi/lo, transposed [H][E] -
__global__ void k_split(const float* __restrict__ w_e,
                        _Float16* __restrict__ w_hiT, _Float16* __restrict__ w_loT) {
    __shared__ _Float16 th[32][33];
    __shared__ _Float16 tl[32][33];
    int e0 = blockIdx.x * 32, h0 = blockIdx.y * 32;
    int tx = threadIdx.x & 31, ty = threadIdx.x >> 5;
#pragma unroll
    for (int i = 0; i < 4; ++i) {
        int r = ty + i * 8;
        float x = w_e[(size_t)(e0 + r) * 1024 + h0 + tx];
        _Float16 h = (_Float16)x;
        th[r][tx] = h;
        tl[r][tx] = (_Float16)(x - (float)h);
    }
    __syncthreads();
#pragma unroll
    for (int i = 0; i < 4; ++i) {
        int r = ty + i * 8;
        w_hiT[(size_t)(h0 + r) * 1024 + e0 + tx] = th[tx][r];
        w_loT[(size_t)(h0 + r) * 1024 + e0 + tx] = tl[tx][r];
    }
}

// ---------------- kernel 2: scores[m] = sum_h w_out[h]*tanh((enc@w_e)[m,h]+dw[b,h])
// fp16x3 split MFMA, 16x16x32. 512 thr (8 waves, 2x4 wave grid), 2 waves/SIMD
// -> 256 VGPR budget. M_TILE=256 (wave owns 128x64: 8m x 4n frags),
// H_CHUNK=256, K_STEP=32, flat tile loop t=0..127 (hc=t>>5, kt=t&31).
// Grid = 256 blocks = 1 pass over 1 block/CU.
//
// r4-proven single-barrier full-dbuf structure (compiler-scheduled waits; no
// manual waitcnt - r5 regression; register-budgeted - r6 spill disaster:
// 1024thr => 128-reg cap => acc spilled to scratch, WRITE_SIZE 1.45GB).
// Live regs/wave: acc 128 + Bfrag 32 + Afrag ~16 + Astage 16 + addr ~= 215.
// Score reduction happens per-hc in the epilogue (no persistent sc regs).
//
// Per tile: issue B gload_lds(t+1 -> buf^1) [4 instrs, 8KB each] |
//   convert+ds_write A(t+1) [2 rows/thread] | A raw loads(t+2) |
//   ds_read frags(cur) | 96 MFMA/wave | one __syncthreads.
//
// Dynamic LDS 132096 B:
//   A buf0 hi/lo: 0 / 16384       A buf1 hi/lo: 32768 / 49152   ([4ks][256r][16B])
//   B buf0 hi/lo: 65536 / 81920   B buf1 hi/lo: 98304 / 114688  ([4ks][256r][16B])
//   scoreL: 131072 (256 f32)
__global__ __launch_bounds__(512, 2)
void k_scores(const float* __restrict__ enc,
              const _Float16* __restrict__ w_hiT, const _Float16* __restrict__ w_loT,
              const float* __restrict__ dw, const float* __restrict__ w_out,
              float* __restrict__ scores) {
    extern __shared__ __align__(16) char smem[];
    float* scoreL = (float*)(smem + 131072);

    const int tid  = threadIdx.x;
    const int lane = tid & 63;
    const int wave = tid >> 6;
    const int wr = wave >> 2, wc = wave & 3;     // 2 x 4 wave grid
    const int m0 = blockIdx.x * 256;
    const int bb = m0 >> 11;
    const float* dwb = dw + bb * 1024;

    // A staging: thread stages rows a_row and a_row+128, kseg a_ks (8 f32 each)
    const int a_row = tid >> 2, a_ks = tid & 3;
    const float* aBase = enc + (size_t)(m0 + a_row) * 1024 + a_ks * 8;
    // B staging via gload_lds (identical to r4)
    const int b_row = tid & 255, b_ks = tid >> 8;
    const _Float16* bhBase = w_hiT + (size_t)b_row * 1024 + b_ks * 8;
    const _Float16* blBase = w_loT + (size_t)b_row * 1024 + b_ks * 8;
    const int wofs = wave * 1024;

    if (tid < 256) scoreL[tid] = 0.f;

    f32x4 acc[8][4];
#pragma unroll
    for (int m = 0; m < 8; ++m)
#pragma unroll
        for (int n = 0; n < 4; ++n) acc[m][n] = (f32x4){0.f, 0.f, 0.f, 0.f};

    float4 pa0, pa1, pa2, pa3;   // raw A prefetch regs (2 rows x 8 f32)

#define A_LOAD(t) do { \
        const float* _p = aBase + (((t) & 31) << 5); \
        pa0 = ((const float4*)_p)[0]; \
        pa1 = ((const float4*)_p)[1]; \
        const float* _p2 = _p + 128 * 1024; \
        pa2 = ((const float4*)_p2)[0]; \
        pa3 = ((const float4*)_p2)[1]; \
    } while (0)
#define B_ISSUE(t, buf) do { \
        const size_t _g = ((size_t)((t) >> 5) << 18) + (size_t)(((t) & 31) << 5); \
        char* _b = smem + 65536 + (buf) * 32768; \
        gload_lds16(bhBase + _g,      _b + wofs); \
        gload_lds16(bhBase + _g + 16, _b + 8192 + wofs); \
        gload_lds16(blBase + _g,      _b + 16384 + wofs); \
        gload_lds16(blBase + _g + 16, _b + 24576 + wofs); \
    } while (0)
#define A_STAGE(buf) do { \
        float _q[16] = {pa0.x, pa0.y, pa0.z, pa0.w, pa1.x, pa1.y, pa1.z, pa1.w, \
                        pa2.x, pa2.y, pa2.z, pa2.w, pa3.x, pa3.y, pa3.z, pa3.w}; \
        half8 _hi0, _lo0, _hi1, _lo1; \
        _Pragma("unroll") \
        for (int _j = 0; _j < 8; ++_j) { \
            _Float16 _h = (_Float16)_q[_j]; \
            _hi0[_j] = _h; \
            _lo0[_j] = (_Float16)(_q[_j] - (float)_h); \
            _Float16 _h2 = (_Float16)_q[_j + 8]; \
            _hi1[_j] = _h2; \
            _lo1[_j] = (_Float16)(_q[_j + 8] - (float)_h2); \
        } \
        char* _a = smem + (buf) * 32768; \
        *(half8*)(_a + a_ks * 4096 + a_row * 16) = _hi0; \
        *(half8*)(_a + 16384 + a_ks * 4096 + a_row * 16) = _lo0; \
        *(half8*)(_a + a_ks * 4096 + (a_row + 128) * 16) = _hi1; \
        *(half8*)(_a + 16384 + a_ks * 4096 + (a_row + 128) * 16) = _lo1; \
    } while (0)

    // prologue: stage tile 0 into buf0, prefetch A(1)
    A_LOAD(0);
    B_ISSUE(0, 0);
    A_STAGE(0);        // compiler waits its own loads, writes Abuf0
    A_LOAD(1);
    __syncthreads();   // drains B(0) gloads too

    const int ks = lane >> 4, rb = lane & 15;

    for (int t = 0; t < 128; ++t) {
        const int cur = t & 1;
        if (t < 127) {
            B_ISSUE(t + 1, cur ^ 1);   // async, lands under the MFMAs below
            A_STAGE(cur ^ 1);
            if (t < 126) A_LOAD(t + 2);
        }
        const char* sa = smem + cur * 32768;
        const char* sb = smem + 65536 + cur * 32768;
        half8 bh[4], bl[4];
#pragma unroll
        for (int n = 0; n < 4; ++n) {
            int off = ks * 4096 + (wc * 64 + n * 16 + rb) * 16;
            bh[n] = *(const half8*)(sb + off);
            bl[n] = *(const half8*)(sb + 16384 + off);
        }
        __builtin_amdgcn_s_setprio(1);
#pragma unroll
        for (int m = 0; m < 8; ++m) {
            int off = ks * 4096 + (wr * 128 + m * 16 + rb) * 16;
            half8 ah = *(const half8*)(sa + off);
            half8 al = *(const half8*)(sa + 16384 + off);
#pragma unroll
            for (int n = 0; n < 4; ++n) {
                acc[m][n] = __builtin_amdgcn_mfma_f32_16x16x32_f16(ah, bh[n], acc[m][n], 0, 0, 0);
                acc[m][n] = __builtin_amdgcn_mfma_f32_16x16x32_f16(ah, bl[n], acc[m][n], 0, 0, 0);
                acc[m][n] = __builtin_amdgcn_mfma_f32_16x16x32_f16(al, bh[n], acc[m][n], 0, 0, 0);
            }
        }
        __builtin_amdgcn_s_setprio(0);

        if ((t & 31) == 31) {
            // epilogue for hc = t>>5: tanh + w_out, reduce, atomicAdd scoreL.
            const int h0 = (t >> 5) << 8;
#pragma unroll
            for (int m = 0; m < 8; ++m) {
                float con[4] = {0.f, 0.f, 0.f, 0.f};
#pragma unroll
                for (int n = 0; n < 4; ++n) {
                    int h = h0 + wc * 64 + n * 16 + rb;
                    float dwv = dwb[h];
                    float wo  = w_out[h];
#pragma unroll
                    for (int r = 0; r < 4; ++r) {
                        float x = acc[m][n][r] + dwv;
                        float e = __expf(2.0f * fabsf(x));
                        float th = copysignf(1.0f - __fdividef(2.0f, e + 1.0f), x);
                        con[r] += th * wo;
                    }
                    acc[m][n] = (f32x4){0.f, 0.f, 0.f, 0.f};
                }
#pragma unroll
                for (int r = 0; r < 4; ++r) {
                    float v = con[r];
                    v += __shfl_xor(v, 1);
                    v += __shfl_xor(v, 2);
                    v += __shfl_xor(v, 4);
                    v += __shfl_xor(v, 8);
                    con[r] = v;
                }
                if ((lane & 15) == 0) {
                    int rbase = wr * 128 + m * 16 + (lane >> 4) * 4;
#pragma unroll
                    for (int r = 0; r < 4; ++r)
                        atomicAdd(&scoreL[rbase + r], con[r]);
                }
            }
        }
        __syncthreads();   // drain vm+lgkm: tile t+1 fully staged; cur freed
    }

    __syncthreads();
    if (tid < 256) scores[m0 + tid] = scoreL[tid];
#undef A_LOAD
#undef B_ISSUE
#undef A_STAGE
}

// ---------------- kernel 3: masked softmax over N per batch ----------------
// mask is bool in python -> pushed as int32.
__global__ void k_softmax(const float* __restrict__ scores,
                          const int* __restrict__ mask,
                          float* __restrict__ probs, float* __restrict__ out_probs) {
    int b = blockIdx.x, tid = threadIdx.x;
    __shared__ float red[8];
    float v[8];
    float m = -INFINITY;
#pragma unroll
    for (int i = 0; i < 8; ++i) {
        int n = tid + i * 256;
        float s = scores[b * 2048 + n];
        s = (mask[b * 2048 + n] != 0) ? s : -INFINITY;
        v[i] = s;
        m = fmaxf(m, s);
    }
    for (int off = 32; off; off >>= 1) m = fmaxf(m, __shfl_xor(m, off));
    if ((tid & 63) == 0) red[tid >> 6] = m;
    __syncthreads();
    m = fmaxf(fmaxf(red[0], red[1]), fmaxf(red[2], red[3]));
    float sum = 0.f;
#pragma unroll
    for (int i = 0; i < 8; ++i) {
        v[i] = expf(v[i] - m);
        sum += v[i];
    }
    for (int off = 32; off; off >>= 1) sum += __shfl_xor(sum, off);
    if ((tid & 63) == 0) red[4 + (tid >> 6)] = sum;
    __syncthreads();
    sum = red[4] + red[5] + red[6] + red[7];
    float inv = 1.0f / sum;
#pragma unroll
    for (int i = 0; i < 8; ++i) {
        int n = tid + i * 256;
        float p = v[i] * inv;
        probs[b * 2048 + n]     = p;
        out_probs[b * 2048 + n] = p;
    }
}

// ---------------- kernel 4: attn[b,e] += sum_n probs[b,n]*enc[b,n,e] --------
// Survivor compaction (softmax is near-one-hot), then unconditional FMA loop.
__global__ void k_attn(const float* __restrict__ probs, const float* __restrict__ enc,
                       float* __restrict__ attn) {
    __shared__ float pv[128];
    __shared__ int   pidx[128];
    __shared__ int   cnt;
    int b = blockIdx.x, c = blockIdx.y, t = threadIdx.x;
    if (t == 0) cnt = 0;
    __syncthreads();
    if (t < 128) {
        float p = probs[b * 2048 + c * 128 + t];
        if (p >= 1e-12f) {
            int slot = atomicAdd(&cnt, 1);
            pv[slot]   = p;
            pidx[slot] = c * 128 + t;
        }
    }
    __syncthreads();
    int nk = cnt;
    if (nk == 0) return;
    const float* eb = enc + (size_t)b * 2048 * 1024;
    float4 acc = {0.f, 0.f, 0.f, 0.f};
    for (int i = 0; i < nk; ++i) {
        float p = pv[i];
        float4 v = ((const float4*)(eb + (size_t)pidx[i] * 1024))[t];
        acc.x += p * v.x;
        acc.y += p * v.y;
        acc.z += p * v.z;
        acc.w += p * v.w;
    }
    float* o = attn + b * 1024 + t * 4;
    atomicAdd(o + 0, acc.x);
    atomicAdd(o + 1, acc.y);
    atomicAdd(o + 2, acc.z);
    atomicAdd(o + 3, acc.w);
}

extern "C" void kernel_launch(void* const* d_in, const int* in_sizes, int n_in,
                              void* d_out, int out_size, void* d_ws, size_t ws_size,
                              hipStream_t stream) {
    const float* enc   = (const float*)d_in[0];  // [32,2048,1024]
    const float* dec   = (const float*)d_in[1];  // [32,1024]
    const int*   mask  = (const int*)d_in[2];    // [32,2048] bool -> int32
    const float* w_e   = (const float*)d_in[3];  // [1024,1024]
    const float* w_d   = (const float*)d_in[4];  // [1024,1024]
    const float* w_out = (const float*)d_in[5];  // [1024]

    float* out_attn  = (float*)d_out;              // [32*1024]
    float* out_probs = out_attn + Bsz * Hdim;      // [32*2048]

    float* dw        = (float*)d_ws;               // 32*1024
    float* scores    = dw + Bsz * Hdim;            // 32*2048
    float* probs     = scores + Bsz * Nseq;        // 32*2048
    _Float16* w_hiT  = (_Float16*)(probs + Bsz * Nseq);  // [1024*1024]
    _Float16* w_loT  = w_hiT + Edim * Hdim;

    static const int kScoresLds = 132096;   // 128 KB bufs + 1 KB scoreL
    hipFuncSetAttribute((const void*)k_scores,
                        hipFuncAttributeMaxDynamicSharedMemorySize, kScoresLds);

    hipMemsetAsync(out_attn, 0, Bsz * Hdim * sizeof(float), stream);
    k_dw<<<dim3(32, 4), dim3(256), 0, stream>>>(dec, w_d, dw);
    k_split<<<dim3(32, 32), dim3(256), 0, stream>>>(w_e, w_hiT, w_loT);
    k_scores<<<dim3(256), dim3(512), kScoresLds, stream>>>(enc, w_hiT, w_loT, dw, w_out, scores);
    k_softmax<<<dim3(32), dim3(256), 0, stream>>>(scores, mask, probs, out_probs);
    k_attn<<<dim3(32, 16), dim3(256), 0, stream>>>(probs, enc, out_attn);
}